// Round 13
// baseline (807.454 us; speedup 1.0000x reference)
//
#include <hip/hip_runtime.h>
#include <hip/hip_bf16.h>

typedef __bf16 bf16;
typedef __attribute__((ext_vector_type(8))) __bf16 bf16x8;
typedef __attribute__((ext_vector_type(4))) __bf16 bf16x4;
typedef __attribute__((ext_vector_type(4))) float f32x4;
typedef __attribute__((ext_vector_type(4))) int i32x4;
typedef __attribute__((ext_vector_type(4))) short s16x4;

constexpr int SLEN = 2048;
constexpr int DH = 64;
constexpr int NBH = 64;                      // B*H = 4*16
constexpr int NT = SLEN / 64;                // 32 k-tiles
constexpr float SCALE_LOG2E = 0.125f * 1.4426950408889634f;  // (1/sqrt(64)) * log2(e)

// ---- fused pre-pass: K fp32->bf16 (coalesced) + V fp32 [s][d] -> bf16 Vt [d][s] ----
__global__ __launch_bounds__(256) void prep_kv_kernel(
    const float* __restrict__ K, const float* __restrict__ V,
    bf16* __restrict__ Kb, bf16* __restrict__ Vt)
{
    __shared__ float t[64][65];
    const int bh = blockIdx.y;
    const int s0 = blockIdx.x * 64;
    const int tx = threadIdx.x & 63, ty = threadIdx.x >> 6;

    // V tile -> LDS
    const float* vp = V + ((size_t)bh * SLEN + s0) * DH;
    #pragma unroll
    for (int r = ty; r < 64; r += 4) t[r][tx] = vp[(size_t)r * DH + tx];

    // K cast (independent of LDS; overlaps the transpose latency)
    {
        const float* kp = K + ((size_t)bh * SLEN + s0) * DH;
        bf16* kbp = Kb + ((size_t)bh * SLEN + s0) * DH;
        int r = threadIdx.x >> 2, c = (threadIdx.x & 3) * 16;
        const float4* src = (const float4*)(kp + (size_t)r * DH + c);
        float4 a = src[0], b = src[1], c2 = src[2], d = src[3];
        bf16x8 o0, o1;
        o0[0]=(bf16)a.x;  o0[1]=(bf16)a.y;  o0[2]=(bf16)a.z;  o0[3]=(bf16)a.w;
        o0[4]=(bf16)b.x;  o0[5]=(bf16)b.y;  o0[6]=(bf16)b.z;  o0[7]=(bf16)b.w;
        o1[0]=(bf16)c2.x; o1[1]=(bf16)c2.y; o1[2]=(bf16)c2.z; o1[3]=(bf16)c2.w;
        o1[4]=(bf16)d.x;  o1[5]=(bf16)d.y;  o1[6]=(bf16)d.z;  o1[7]=(bf16)d.w;
        *(bf16x8*)(kbp + (size_t)r * DH + c)     = o0;
        *(bf16x8*)(kbp + (size_t)r * DH + c + 8) = o1;
    }

    __syncthreads();
    bf16* op = Vt + (size_t)bh * DH * SLEN + s0;
    #pragma unroll
    for (int r = ty; r < 64; r += 4) op[(size_t)r * SLEN + tx] = (bf16)t[tx][r];
}

// async global->LDS, 16B per lane, dest = wave-uniform base + lane*16
__device__ __forceinline__ void gl_lds16(const void* g, void* l) {
    __builtin_amdgcn_global_load_lds(
        (const __attribute__((address_space(1))) void*)g,
        (__attribute__((address_space(3))) void*)l, 16, 0, 0);
}

// 16x16x16 bf16 MFMA (instruction exists on gfx950: cdna4_isa §10).
__device__ __forceinline__ f32x4 pv_mfma(bf16x4 a, bf16x4 b, f32x4 c) {
#if __has_builtin(__builtin_amdgcn_mfma_f32_16x16x16bf16_1k)
    return __builtin_amdgcn_mfma_f32_16x16x16bf16_1k(
        __builtin_bit_cast(s16x4, a), __builtin_bit_cast(s16x4, b), c, 0, 0, 0);
#else
    f32x4 d;
    asm("s_nop 1\n\t"
        "v_mfma_f32_16x16x16_bf16 %0, %1, %2, %3\n\t"
        "s_nop 7"
        : "=v"(d) : "v"(a), "v"(b), "v"(c));
    return d;
#endif
}

// ---- main attention kernel ----
// vs R12 (one goal: halve the per-round fixed overhead): 128 q-rows/block,
// each wave owns 32 rows as 2 fragment groups g=0,1 (rows w*32+g*16+lq).
// Round count halves (1024 blocks x 32 tiles), K/Vt HBM reads halve
// (16 blocks/bh share each 512KB panel). K/V tile + staging + counted-vmcnt
// schedule unchanged. Single raw[4] mask buffer serves both groups:
//   compress g1(kt) -> load g0(kt+1) -> body_g0 -> compress g0(kt+1)
//   -> load g1(kt+1) -> body_g1 -> sync
// (each compress waits on >=900-cyc-old loads, covered by a body phase).
// LDS 32KB, launch_bounds(256,4): ~115 VGPR target, 4 blocks/CU = 128KB.
// K/V LDS rows swizzled byte^=(row&7)<<4 on the GLOBAL SOURCE side, mirrored
// on reads. XCD-bijective swizzle (1024 blocks, %8==0): XCD x owns bh 8x..+7.
// Swapped QK^T: lane (lq,lg) holds scores for q-row g*16+lq, k=n*16+lg*4+i.
// masked_fill is 0 (not -inf), |s|<=~7 -> unnormalized exp safe; one divide.
__global__ __launch_bounds__(256, 4) void attn_kernel(
    const float* __restrict__ Q, const int* __restrict__ mask,
    const bf16* __restrict__ Kb, const bf16* __restrict__ Vtb,
    float* __restrict__ out)
{
    __shared__ char KT[2][8192];
    __shared__ char VT[2][8192];

    const int h = blockIdx.x;                     // 1024 blocks
    const int logical = (h & 7) * 128 + (h >> 3);
    const int bh = logical >> 4;
    const int qbase = (logical & 15) * 128;
    const int tid = threadIdx.x;
    const int w = tid >> 6, l = tid & 63;
    const int lq = l & 15, lg = l >> 4;
    const int qrow_w = qbase + w * 32;            // wave's 32 q-rows

    const char* kgb = (const char*)(Kb + (size_t)bh * SLEN * DH);      // rows 128B
    const char* vgb = (const char*)(Vtb + (size_t)bh * DH * SLEN);     // rows 4096B

    // staging geometry: lane covers (row octet kv_r, swizzled 16B col kv_c)
    const int kv_r = l >> 3;                             // 0..7
    const int kv_c = ((l & 7) * 16) ^ (kv_r << 4);

    // Q B-frags per group (q-col = lq, k = t*32+lg*8+j), hoisted fp32->bf16
    bf16x8 aq[2][2];
    #pragma unroll
    for (int g = 0; g < 2; ++g) {
        const float* qp = Q + ((size_t)bh * SLEN + qrow_w + g * 16 + lq) * DH + lg * 8;
        #pragma unroll
        for (int t = 0; t < 2; ++t) {
            float4 x = *(const float4*)(qp + t * 32);
            float4 y = *(const float4*)(qp + t * 32 + 4);
            bf16x8 f;
            f[0]=(bf16)x.x; f[1]=(bf16)x.y; f[2]=(bf16)x.z; f[3]=(bf16)x.w;
            f[4]=(bf16)y.x; f[5]=(bf16)y.y; f[6]=(bf16)y.z; f[7]=(bf16)y.w;
            aq[g][t] = f;
        }
    }

    f32x4 acc[2][4] = {{{0,0,0,0},{0,0,0,0},{0,0,0,0},{0,0,0,0}},
                       {{0,0,0,0},{0,0,0,0},{0,0,0,0},{0,0,0,0}}};
    float dpart[2] = {0.f, 0.f};
    const int swzk = (lq & 7) << 4;      // read-side XOR, row%8 == lq%8

    const int* mrow0 = mask + ((size_t)bh * SLEN + qrow_w + lq) * SLEN;
    const int* mrow1 = mrow0 + (size_t)16 * SLEN;

    // K/V staging for k-tile index t: 4 gl_lds per wave (2 K + 2 V)
    auto stage = [&](int t, int buf) {
        const int kb = t * 64;                           // element offset
        #pragma unroll
        for (int q = 0; q < 2; ++q) {
            int r = (w * 2 + q) * 8 + kv_r;              // tile row 0..63
            gl_lds16(kgb + (size_t)(kb + r) * 128 + kv_c, &KT[buf][(w * 2 + q) * 1024]);
            gl_lds16(vgb + (size_t)r * 4096 + (size_t)kb * 2 + kv_c, &VT[buf][(w * 2 + q) * 1024]);
        }
    };
    auto loadmask = [&](int t, const int* mr, i32x4* m) {
        #pragma unroll
        for (int n = 0; n < 4; ++n)
            m[n] = __builtin_nontemporal_load((const i32x4*)(mr + t * 64 + n * 16 + lg * 4));
    };
    auto compress = [&](const i32x4* m, unsigned* pm) {
        #pragma unroll
        for (int n = 0; n < 4; ++n)
            pm[n] = (m[n][0] != 0 ? 1u : 0u) | (m[n][1] != 0 ? 2u : 0u)
                  | (m[n][2] != 0 ? 4u : 0u) | (m[n][3] != 0 ? 8u : 0u);
    };
    // one k-tile of compute for group g: LDS buf `cur`, packed nibbles pm[4]
    auto body = [&](int cur, int g, const unsigned* pm) {
        bf16x4 p[4];
        #pragma unroll
        for (int n = 0; n < 4; ++n) {
            f32x4 s = {0, 0, 0, 0};
            #pragma unroll
            for (int t = 0; t < 2; ++t) {
                bf16x8 bk = *(const bf16x8*)&KT[cur][(n * 16 + lq) * 128 + ((t * 64 + lg * 16) ^ swzk)];
                s = __builtin_amdgcn_mfma_f32_16x16x32_bf16(bk, aq[g][t], s, 0, 0, 0);
            }
            #pragma unroll
            for (int i = 0; i < 4; ++i) {
                float pe = exp2f(s[i] * SCALE_LOG2E);
                pe = ((pm[n] >> i) & 1u) ? 1.0f : pe;    // masked score 0 -> weight 1
                dpart[g] += pe;
                p[n][i] = (bf16)pe;
            }
        }
        #pragma unroll
        for (int nn = 0; nn < 4; ++nn) {
            #pragma unroll
            for (int n = 0; n < 4; ++n) {
                bf16x4 bv = *(const bf16x4*)&VT[cur][(nn * 16 + lq) * 128 + ((n * 32 + lg * 8) ^ swzk)];
                acc[g][nn] = pv_mfma(p[n], bv, acc[g][nn]);
            }
        }
    };
    // counted sync: gl_lds (older) retired, DS pipe drained; 4 mask loads
    // (newest) stay in flight across the barrier.
    auto tile_sync = [&]() {
        asm volatile("s_waitcnt vmcnt(4) lgkmcnt(0)" ::: "memory");
        __builtin_amdgcn_s_barrier();
        __builtin_amdgcn_sched_barrier(0);
    };

    i32x4 raw[4];              // shared mask load buffer (both groups)
    unsigned pm0[4], pm1[4];   // packed nibbles: group0 / group1 of current tile

    // prologue: tile 0 -> buf0; g0(0) masks -> raw -> pm0; g1(0) -> raw (in flight)
    stage(0, 0);
    __builtin_amdgcn_sched_barrier(0);   // keep mask loads newer than gl_lds
    loadmask(0, mrow0, raw);
    tile_sync();
    compress(raw, pm0);
    loadmask(0, mrow1, raw);
    __builtin_amdgcn_sched_barrier(0);

    int cur = 0;
    for (int kt = 0; kt < NT; ++kt) {
        const bool more = (kt + 1) < NT;                 // wave-uniform
        if (more) stage(kt + 1, cur ^ 1);                // K/V prefetch first
        __builtin_amdgcn_sched_barrier(0);
        compress(raw, pm1);                              // g1(kt), loaded ~1 round ago
        if (more) loadmask(kt + 1, mrow0, raw);          // g0(kt+1)
        __builtin_amdgcn_sched_barrier(0);
        body(cur, 0, pm0);
        __builtin_amdgcn_sched_barrier(0);
        if (more) {
            compress(raw, pm0);                          // g0(kt+1), covered by body_g0
            loadmask(kt + 1, mrow1, raw);                // g1(kt+1)
        }
        __builtin_amdgcn_sched_barrier(0);
        body(cur, 1, pm1);
        if (more) { tile_sync(); cur ^= 1; }
    }

    // epilogue per group: denom reduce + normalized write
    #pragma unroll
    for (int g = 0; g < 2; ++g) {
        float d = dpart[g];
        d += __shfl_xor(d, 16, 64);
        d += __shfl_xor(d, 32, 64);
        float dinv = 1.0f / d;
        float di[4];
        #pragma unroll
        for (int i = 0; i < 4; ++i) di[i] = __shfl(dinv, lg * 4 + i, 64);

        float* op = out + ((size_t)bh * SLEN + qrow_w + g * 16) * DH;
        #pragma unroll
        for (int n = 0; n < 4; ++n) {
            #pragma unroll
            for (int i = 0; i < 4; ++i)
                op[(size_t)(lg * 4 + i) * DH + n * 16 + lq] = acc[g][n][i] * di[i];
        }
    }
}

extern "C" void kernel_launch(void* const* d_in, const int* in_sizes, int n_in,
                              void* d_out, int out_size, void* d_ws, size_t ws_size,
                              hipStream_t stream) {
    const float* Q    = (const float*)d_in[0];
    const float* K    = (const float*)d_in[1];
    const float* V    = (const float*)d_in[2];
    const int*   mask = (const int*)d_in[3];
    float* out = (float*)d_out;

    bf16* Kb  = (bf16*)d_ws;                       // 16 MB
    bf16* Vtb = Kb + (size_t)NBH * SLEN * DH;      // 16 MB

    prep_kv_kernel<<<dim3(SLEN / 64, NBH), 256, 0, stream>>>(K, V, Kb, Vtb);
    attn_kernel<<<1024, 256, 0, stream>>>(Q, mask, Kb, Vtb, out);
}

// Round 14
// 708.512 us; speedup vs baseline: 1.1396x; 1.1396x over previous
//
#include <hip/hip_runtime.h>
#include <hip/hip_bf16.h>

typedef __bf16 bf16;
typedef __attribute__((ext_vector_type(8))) __bf16 bf16x8;
typedef __attribute__((ext_vector_type(4))) __bf16 bf16x4;
typedef __attribute__((ext_vector_type(4))) float f32x4;
typedef __attribute__((ext_vector_type(4))) int i32x4;
typedef __attribute__((ext_vector_type(4))) short s16x4;

constexpr int SLEN = 2048;
constexpr int DH = 64;
constexpr int NBH = 64;                      // B*H = 4*16
constexpr int NT = SLEN / 64;                // 32 k-tiles
constexpr float SCALE_LOG2E = 0.125f * 1.4426950408889634f;  // (1/sqrt(64)) * log2(e)

// ---- fused pre-pass: K fp32->bf16 (coalesced) + V fp32 [s][d] -> bf16 Vt [d][s] ----
__global__ __launch_bounds__(256) void prep_kv_kernel(
    const float* __restrict__ K, const float* __restrict__ V,
    bf16* __restrict__ Kb, bf16* __restrict__ Vt)
{
    __shared__ float t[64][65];
    const int bh = blockIdx.y;
    const int s0 = blockIdx.x * 64;
    const int tx = threadIdx.x & 63, ty = threadIdx.x >> 6;

    // V tile -> LDS
    const float* vp = V + ((size_t)bh * SLEN + s0) * DH;
    #pragma unroll
    for (int r = ty; r < 64; r += 4) t[r][tx] = vp[(size_t)r * DH + tx];

    // K cast (independent of LDS; overlaps the transpose latency)
    {
        const float* kp = K + ((size_t)bh * SLEN + s0) * DH;
        bf16* kbp = Kb + ((size_t)bh * SLEN + s0) * DH;
        int r = threadIdx.x >> 2, c = (threadIdx.x & 3) * 16;
        const float4* src = (const float4*)(kp + (size_t)r * DH + c);
        float4 a = src[0], b = src[1], c2 = src[2], d = src[3];
        bf16x8 o0, o1;
        o0[0]=(bf16)a.x;  o0[1]=(bf16)a.y;  o0[2]=(bf16)a.z;  o0[3]=(bf16)a.w;
        o0[4]=(bf16)b.x;  o0[5]=(bf16)b.y;  o0[6]=(bf16)b.z;  o0[7]=(bf16)b.w;
        o1[0]=(bf16)c2.x; o1[1]=(bf16)c2.y; o1[2]=(bf16)c2.z; o1[3]=(bf16)c2.w;
        o1[4]=(bf16)d.x;  o1[5]=(bf16)d.y;  o1[6]=(bf16)d.z;  o1[7]=(bf16)d.w;
        *(bf16x8*)(kbp + (size_t)r * DH + c)     = o0;
        *(bf16x8*)(kbp + (size_t)r * DH + c + 8) = o1;
    }

    __syncthreads();
    bf16* op = Vt + (size_t)bh * DH * SLEN + s0;
    #pragma unroll
    for (int r = ty; r < 64; r += 4) op[(size_t)r * SLEN + tx] = (bf16)t[tx][r];
}

// async global->LDS, 16B per lane, dest = wave-uniform base + lane*16
__device__ __forceinline__ void gl_lds16(const void* g, void* l) {
    __builtin_amdgcn_global_load_lds(
        (const __attribute__((address_space(1))) void*)g,
        (__attribute__((address_space(3))) void*)l, 16, 0, 0);
}

// 16x16x16 bf16 MFMA (instruction exists on gfx950: cdna4_isa §10).
__device__ __forceinline__ f32x4 pv_mfma(bf16x4 a, bf16x4 b, f32x4 c) {
#if __has_builtin(__builtin_amdgcn_mfma_f32_16x16x16bf16_1k)
    return __builtin_amdgcn_mfma_f32_16x16x16bf16_1k(
        __builtin_bit_cast(s16x4, a), __builtin_bit_cast(s16x4, b), c, 0, 0, 0);
#else
    f32x4 d;
    asm("s_nop 1\n\t"
        "v_mfma_f32_16x16x16_bf16 %0, %1, %2, %3\n\t"
        "s_nop 7"
        : "=v"(d) : "v"(a), "v"(b), "v"(c));
    return d;
#endif
}

// ---- main attention kernel ----
// R13 retry with the spill fixed. 128 q-rows/block, each wave owns 32 rows
// as 2 groups (g0: rows w*32+lq, g1: rows w*32+16+lq). R13's failure (807us,
// WRITE_SIZE 1.3GB) was rule-#20: body(g) with runtime g made acc[g]/aq[g]/
// dpart[g] runtime-indexed -> scratch. Now ALL per-group state is named
// (aq0/aq1, acc0/acc1, dpart0/dpart1, pm0/pm1) and body0/body1 are separate
// lambdas closing over their own names — zero dynamic register indexing.
// Mask schedule (dual raw buffers): per round issue {maskA, maskB} THEN
// {4 gl_lds}; bodies run while all 12 loads fly; compress after body1 (pinned
// by sched_barrier) retires only the mask loads; tile_sync vmcnt(0) then
// finds gl_lds already landed. K/V LDS rows swizzled byte^=(row&7)<<4 on the
// GLOBAL SOURCE side, mirrored on reads. LDS 32KB, launch_bounds(256,4).
// XCD-bijective swizzle (1024 blocks): XCD x owns bh 8x..8x+7.
// Swapped QK^T: lane (lq,lg) holds scores for its q-row, k=n*16+lg*4+i.
// masked_fill is 0 (not -inf), |s|<=~7 -> unnormalized exp safe; one divide.
__global__ __launch_bounds__(256, 4) void attn_kernel(
    const float* __restrict__ Q, const int* __restrict__ mask,
    const bf16* __restrict__ Kb, const bf16* __restrict__ Vtb,
    float* __restrict__ out)
{
    __shared__ char KT[2][8192];
    __shared__ char VT[2][8192];

    const int h = blockIdx.x;                     // 1024 blocks
    const int logical = (h & 7) * 128 + (h >> 3);
    const int bh = logical >> 4;
    const int qbase = (logical & 15) * 128;
    const int tid = threadIdx.x;
    const int w = tid >> 6, l = tid & 63;
    const int lq = l & 15, lg = l >> 4;
    const int qrow_w = qbase + w * 32;            // wave's 32 q-rows

    const char* kgb = (const char*)(Kb + (size_t)bh * SLEN * DH);      // rows 128B
    const char* vgb = (const char*)(Vtb + (size_t)bh * DH * SLEN);     // rows 4096B

    // staging geometry: lane covers (row octet kv_r, swizzled 16B col kv_c)
    const int kv_r = l >> 3;                             // 0..7
    const int kv_c = ((l & 7) * 16) ^ (kv_r << 4);

    // Q B-frags, one per group (q-col = lq, k = t*32+lg*8+j), fp32->bf16
    bf16x8 aq0[2], aq1[2];
    {
        const float* qp0 = Q + ((size_t)bh * SLEN + qrow_w + lq) * DH + lg * 8;
        #pragma unroll
        for (int t = 0; t < 2; ++t) {
            float4 x = *(const float4*)(qp0 + t * 32);
            float4 y = *(const float4*)(qp0 + t * 32 + 4);
            bf16x8 f;
            f[0]=(bf16)x.x; f[1]=(bf16)x.y; f[2]=(bf16)x.z; f[3]=(bf16)x.w;
            f[4]=(bf16)y.x; f[5]=(bf16)y.y; f[6]=(bf16)y.z; f[7]=(bf16)y.w;
            aq0[t] = f;
        }
        const float* qp1 = qp0 + (size_t)16 * DH;
        #pragma unroll
        for (int t = 0; t < 2; ++t) {
            float4 x = *(const float4*)(qp1 + t * 32);
            float4 y = *(const float4*)(qp1 + t * 32 + 4);
            bf16x8 f;
            f[0]=(bf16)x.x; f[1]=(bf16)x.y; f[2]=(bf16)x.z; f[3]=(bf16)x.w;
            f[4]=(bf16)y.x; f[5]=(bf16)y.y; f[6]=(bf16)y.z; f[7]=(bf16)y.w;
            aq1[t] = f;
        }
    }

    f32x4 acc0[4] = {{0,0,0,0},{0,0,0,0},{0,0,0,0},{0,0,0,0}};
    f32x4 acc1[4] = {{0,0,0,0},{0,0,0,0},{0,0,0,0},{0,0,0,0}};
    float dpart0 = 0.f, dpart1 = 0.f;
    const int swzk = (lq & 7) << 4;      // read-side XOR, row%8 == lq%8

    const int* mrow0 = mask + ((size_t)bh * SLEN + qrow_w + lq) * SLEN;
    const int* mrow1 = mrow0 + (size_t)16 * SLEN;

    // K/V staging for k-tile index t: 4 gl_lds per wave (2 K + 2 V)
    auto stage = [&](int t, int buf) {
        const int kb = t * 64;                           // element offset
        #pragma unroll
        for (int q = 0; q < 2; ++q) {
            int r = (w * 2 + q) * 8 + kv_r;              // tile row 0..63
            gl_lds16(kgb + (size_t)(kb + r) * 128 + kv_c, &KT[buf][(w * 2 + q) * 1024]);
            gl_lds16(vgb + (size_t)r * 4096 + (size_t)kb * 2 + kv_c, &VT[buf][(w * 2 + q) * 1024]);
        }
    };
    auto loadmask = [&](int t, const int* mr, i32x4* m) {
        #pragma unroll
        for (int n = 0; n < 4; ++n)
            m[n] = __builtin_nontemporal_load((const i32x4*)(mr + t * 64 + n * 16 + lg * 4));
    };
    auto compress = [&](const i32x4* m, unsigned* pm) {
        #pragma unroll
        for (int n = 0; n < 4; ++n)
            pm[n] = (m[n][0] != 0 ? 1u : 0u) | (m[n][1] != 0 ? 2u : 0u)
                  | (m[n][2] != 0 ? 4u : 0u) | (m[n][3] != 0 ? 8u : 0u);
    };

    i32x4 rawA[4], rawB[4];    // per-group mask load buffers
    unsigned pm0[4], pm1[4];   // packed nibbles for the CURRENT tile

    // group bodies: separate lambdas, each over its own named state only
    auto body0 = [&](int cur) {
        bf16x4 p[4];
        #pragma unroll
        for (int n = 0; n < 4; ++n) {
            f32x4 s = {0, 0, 0, 0};
            #pragma unroll
            for (int t = 0; t < 2; ++t) {
                bf16x8 bk = *(const bf16x8*)&KT[cur][(n * 16 + lq) * 128 + ((t * 64 + lg * 16) ^ swzk)];
                s = __builtin_amdgcn_mfma_f32_16x16x32_bf16(bk, aq0[t], s, 0, 0, 0);
            }
            #pragma unroll
            for (int i = 0; i < 4; ++i) {
                float pe = exp2f(s[i] * SCALE_LOG2E);
                pe = ((pm0[n] >> i) & 1u) ? 1.0f : pe;   // masked score 0 -> weight 1
                dpart0 += pe;
                p[n][i] = (bf16)pe;
            }
        }
        #pragma unroll
        for (int nn = 0; nn < 4; ++nn) {
            #pragma unroll
            for (int n = 0; n < 4; ++n) {
                bf16x4 bv = *(const bf16x4*)&VT[cur][(nn * 16 + lq) * 128 + ((n * 32 + lg * 8) ^ swzk)];
                acc0[nn] = pv_mfma(p[n], bv, acc0[nn]);
            }
        }
    };
    auto body1 = [&](int cur) {
        bf16x4 p[4];
        #pragma unroll
        for (int n = 0; n < 4; ++n) {
            f32x4 s = {0, 0, 0, 0};
            #pragma unroll
            for (int t = 0; t < 2; ++t) {
                bf16x8 bk = *(const bf16x8*)&KT[cur][(n * 16 + lq) * 128 + ((t * 64 + lg * 16) ^ swzk)];
                s = __builtin_amdgcn_mfma_f32_16x16x32_bf16(bk, aq1[t], s, 0, 0, 0);
            }
            #pragma unroll
            for (int i = 0; i < 4; ++i) {
                float pe = exp2f(s[i] * SCALE_LOG2E);
                pe = ((pm1[n] >> i) & 1u) ? 1.0f : pe;
                dpart1 += pe;
                p[n][i] = (bf16)pe;
            }
        }
        #pragma unroll
        for (int nn = 0; nn < 4; ++nn) {
            #pragma unroll
            for (int n = 0; n < 4; ++n) {
                bf16x4 bv = *(const bf16x4*)&VT[cur][(nn * 16 + lq) * 128 + ((n * 32 + lg * 8) ^ swzk)];
                acc1[nn] = pv_mfma(p[n], bv, acc1[nn]);
            }
        }
    };
    auto tile_sync = [&]() {
        asm volatile("s_waitcnt vmcnt(0) lgkmcnt(0)" ::: "memory");
        __builtin_amdgcn_s_barrier();
        __builtin_amdgcn_sched_barrier(0);
    };

    // prologue: masks(0) for both groups, then stage(0); compress waits only
    // on the mask loads (gl_lds newest, stays in flight), then sync.
    loadmask(0, mrow0, rawA);
    loadmask(0, mrow1, rawB);
    __builtin_amdgcn_sched_barrier(0);
    stage(0, 0);
    __builtin_amdgcn_sched_barrier(0);
    compress(rawA, pm0);
    compress(rawB, pm1);
    tile_sync();

    int cur = 0;
    for (int kt = 0; kt < NT; ++kt) {
        const bool more = (kt + 1) < NT;                 // wave-uniform
        if (more) {
            loadmask(kt + 1, mrow0, rawA);               // masks first (older)
            loadmask(kt + 1, mrow1, rawB);
            __builtin_amdgcn_sched_barrier(0);
            stage(kt + 1, cur ^ 1);                      // gl_lds newest
        }
        __builtin_amdgcn_sched_barrier(0);
        body0(cur);
        body1(cur);
        __builtin_amdgcn_sched_barrier(0);               // pin compress below bodies
        if (more) {
            compress(rawA, pm0);                         // retires masks only
            compress(rawB, pm1);
            tile_sync();                                 // gl_lds landed under bodies
            cur ^= 1;
        }
    }

    // epilogue: per-group denom reduce + normalized write
    {
        float d = dpart0;
        d += __shfl_xor(d, 16, 64);
        d += __shfl_xor(d, 32, 64);
        float dinv = 1.0f / d;
        float di[4];
        #pragma unroll
        for (int i = 0; i < 4; ++i) di[i] = __shfl(dinv, lg * 4 + i, 64);
        float* op = out + ((size_t)bh * SLEN + qrow_w) * DH;
        #pragma unroll
        for (int n = 0; n < 4; ++n)
            #pragma unroll
            for (int i = 0; i < 4; ++i)
                op[(size_t)(lg * 4 + i) * DH + n * 16 + lq] = acc0[n][i] * di[i];
    }
    {
        float d = dpart1;
        d += __shfl_xor(d, 16, 64);
        d += __shfl_xor(d, 32, 64);
        float dinv = 1.0f / d;
        float di[4];
        #pragma unroll
        for (int i = 0; i < 4; ++i) di[i] = __shfl(dinv, lg * 4 + i, 64);
        float* op = out + ((size_t)bh * SLEN + qrow_w + 16) * DH;
        #pragma unroll
        for (int n = 0; n < 4; ++n)
            #pragma unroll
            for (int i = 0; i < 4; ++i)
                op[(size_t)(lg * 4 + i) * DH + n * 16 + lq] = acc1[n][i] * di[i];
    }
}

extern "C" void kernel_launch(void* const* d_in, const int* in_sizes, int n_in,
                              void* d_out, int out_size, void* d_ws, size_t ws_size,
                              hipStream_t stream) {
    const float* Q    = (const float*)d_in[0];
    const float* K    = (const float*)d_in[1];
    const float* V    = (const float*)d_in[2];
    const int*   mask = (const int*)d_in[3];
    float* out = (float*)d_out;

    bf16* Kb  = (bf16*)d_ws;                       // 16 MB
    bf16* Vtb = Kb + (size_t)NBH * SLEN * DH;      // 16 MB

    prep_kv_kernel<<<dim3(SLEN / 64, NBH), 256, 0, stream>>>(K, V, Kb, Vtb);
    attn_kernel<<<1024, 256, 0, stream>>>(Q, mask, Kb, Vtb, out);
}

// Round 15
// 544.843 us; speedup vs baseline: 1.4820x; 1.3004x over previous
//
#include <hip/hip_runtime.h>
#include <hip/hip_bf16.h>

typedef __bf16 bf16;
typedef __attribute__((ext_vector_type(8))) __bf16 bf16x8;
typedef __attribute__((ext_vector_type(4))) __bf16 bf16x4;
typedef __attribute__((ext_vector_type(4))) float f32x4;
typedef __attribute__((ext_vector_type(4))) int i32x4;
typedef __attribute__((ext_vector_type(4))) short s16x4;

constexpr int SLEN = 2048;
constexpr int DH = 64;
constexpr int NBH = 64;                      // B*H = 4*16
constexpr int NT = SLEN / 64;                // 32 k-tiles
constexpr float SCALE_LOG2E = 0.125f * 1.4426950408889634f;  // (1/sqrt(64)) * log2(e)

// ---- fused pre-pass: K fp32->bf16 (coalesced) + V fp32 [s][d] -> bf16 Vt [d][s] ----
__global__ __launch_bounds__(256) void prep_kv_kernel(
    const float* __restrict__ K, const float* __restrict__ V,
    bf16* __restrict__ Kb, bf16* __restrict__ Vt)
{
    __shared__ float t[64][65];
    const int bh = blockIdx.y;
    const int s0 = blockIdx.x * 64;
    const int tx = threadIdx.x & 63, ty = threadIdx.x >> 6;

    // V tile -> LDS
    const float* vp = V + ((size_t)bh * SLEN + s0) * DH;
    #pragma unroll
    for (int r = ty; r < 64; r += 4) t[r][tx] = vp[(size_t)r * DH + tx];

    // K cast (independent of LDS; overlaps the transpose latency)
    {
        const float* kp = K + ((size_t)bh * SLEN + s0) * DH;
        bf16* kbp = Kb + ((size_t)bh * SLEN + s0) * DH;
        int r = threadIdx.x >> 2, c = (threadIdx.x & 3) * 16;
        const float4* src = (const float4*)(kp + (size_t)r * DH + c);
        float4 a = src[0], b = src[1], c2 = src[2], d = src[3];
        bf16x8 o0, o1;
        o0[0]=(bf16)a.x;  o0[1]=(bf16)a.y;  o0[2]=(bf16)a.z;  o0[3]=(bf16)a.w;
        o0[4]=(bf16)b.x;  o0[5]=(bf16)b.y;  o0[6]=(bf16)b.z;  o0[7]=(bf16)b.w;
        o1[0]=(bf16)c2.x; o1[1]=(bf16)c2.y; o1[2]=(bf16)c2.z; o1[3]=(bf16)c2.w;
        o1[4]=(bf16)d.x;  o1[5]=(bf16)d.y;  o1[6]=(bf16)d.z;  o1[7]=(bf16)d.w;
        *(bf16x8*)(kbp + (size_t)r * DH + c)     = o0;
        *(bf16x8*)(kbp + (size_t)r * DH + c + 8) = o1;
    }

    __syncthreads();
    bf16* op = Vt + (size_t)bh * DH * SLEN + s0;
    #pragma unroll
    for (int r = ty; r < 64; r += 4) op[(size_t)r * SLEN + tx] = (bf16)t[tx][r];
}

// async global->LDS, 16B per lane, dest = wave-uniform base + lane*16
__device__ __forceinline__ void gl_lds16(const void* g, void* l) {
    __builtin_amdgcn_global_load_lds(
        (const __attribute__((address_space(1))) void*)g,
        (__attribute__((address_space(3))) void*)l, 16, 0, 0);
}

// 16x16x16 bf16 MFMA (instruction exists on gfx950: cdna4_isa §10).
__device__ __forceinline__ f32x4 pv_mfma(bf16x4 a, bf16x4 b, f32x4 c) {
#if __has_builtin(__builtin_amdgcn_mfma_f32_16x16x16bf16_1k)
    return __builtin_amdgcn_mfma_f32_16x16x16bf16_1k(
        __builtin_bit_cast(s16x4, a), __builtin_bit_cast(s16x4, b), c, 0, 0, 0);
#else
    f32x4 d;
    asm("s_nop 1\n\t"
        "v_mfma_f32_16x16x16_bf16 %0, %1, %2, %3\n\t"
        "s_nop 7"
        : "=v"(d) : "v"(a), "v"(b), "v"(c));
    return d;
#endif
}

// ---- main attention kernel ----
// 128 q-rows/block, 2 named groups per wave (g0: rows w*32+lq, g1: +16).
// R14 still spilled (~1GB scratch writes): launch_bounds(256,4) caps the
// unified file at 128/lane, split 64 arch-VGPR + 64 AGPR by the allocator;
// the ~84-reg arch working set (rawA/rawB mask buffers are the long-lived
// part) spilled. R15: launch_bounds(256,3) -> ~170 cap, arch side fits.
// Also per-n fused PV: each p_n is consumed by its 4 PV MFMAs immediately
// (shorter live ranges, -6 regs). 12 waves/CU (3 blocks x 32KB LDS).
// Mask schedule: per round issue {maskA, maskB} then {4 gl_lds}; bodies run
// while all 12 loads fly; compress after body1 retires only mask loads;
// tile_sync vmcnt(0) finds gl_lds already landed.
// K/V LDS rows swizzled byte^=(row&7)<<4 on the GLOBAL SOURCE side, mirrored
// on reads. XCD-bijective swizzle (1024 blocks): XCD x owns bh 8x..8x+7.
// Swapped QK^T: lane (lq,lg) holds scores for its q-row, k=n*16+lg*4+i.
// masked_fill is 0 (not -inf), |s|<=~7 -> unnormalized exp safe; one divide.
__global__ __launch_bounds__(256, 3) void attn_kernel(
    const float* __restrict__ Q, const int* __restrict__ mask,
    const bf16* __restrict__ Kb, const bf16* __restrict__ Vtb,
    float* __restrict__ out)
{
    __shared__ char KT[2][8192];
    __shared__ char VT[2][8192];

    const int h = blockIdx.x;                     // 1024 blocks
    const int logical = (h & 7) * 128 + (h >> 3);
    const int bh = logical >> 4;
    const int qbase = (logical & 15) * 128;
    const int tid = threadIdx.x;
    const int w = tid >> 6, l = tid & 63;
    const int lq = l & 15, lg = l >> 4;
    const int qrow_w = qbase + w * 32;            // wave's 32 q-rows

    const char* kgb = (const char*)(Kb + (size_t)bh * SLEN * DH);      // rows 128B
    const char* vgb = (const char*)(Vtb + (size_t)bh * DH * SLEN);     // rows 4096B

    // staging geometry: lane covers (row octet kv_r, swizzled 16B col kv_c)
    const int kv_r = l >> 3;                             // 0..7
    const int kv_c = ((l & 7) * 16) ^ (kv_r << 4);

    // Q B-frags, one per group (q-col = lq, k = t*32+lg*8+j), fp32->bf16
    bf16x8 aq0[2], aq1[2];
    {
        const float* qp0 = Q + ((size_t)bh * SLEN + qrow_w + lq) * DH + lg * 8;
        #pragma unroll
        for (int t = 0; t < 2; ++t) {
            float4 x = *(const float4*)(qp0 + t * 32);
            float4 y = *(const float4*)(qp0 + t * 32 + 4);
            bf16x8 f;
            f[0]=(bf16)x.x; f[1]=(bf16)x.y; f[2]=(bf16)x.z; f[3]=(bf16)x.w;
            f[4]=(bf16)y.x; f[5]=(bf16)y.y; f[6]=(bf16)y.z; f[7]=(bf16)y.w;
            aq0[t] = f;
        }
        const float* qp1 = qp0 + (size_t)16 * DH;
        #pragma unroll
        for (int t = 0; t < 2; ++t) {
            float4 x = *(const float4*)(qp1 + t * 32);
            float4 y = *(const float4*)(qp1 + t * 32 + 4);
            bf16x8 f;
            f[0]=(bf16)x.x; f[1]=(bf16)x.y; f[2]=(bf16)x.z; f[3]=(bf16)x.w;
            f[4]=(bf16)y.x; f[5]=(bf16)y.y; f[6]=(bf16)y.z; f[7]=(bf16)y.w;
            aq1[t] = f;
        }
    }

    f32x4 acc0[4] = {{0,0,0,0},{0,0,0,0},{0,0,0,0},{0,0,0,0}};
    f32x4 acc1[4] = {{0,0,0,0},{0,0,0,0},{0,0,0,0},{0,0,0,0}};
    float dpart0 = 0.f, dpart1 = 0.f;
    const int swzk = (lq & 7) << 4;      // read-side XOR, row%8 == lq%8

    const int* mrow0 = mask + ((size_t)bh * SLEN + qrow_w + lq) * SLEN;
    const int* mrow1 = mrow0 + (size_t)16 * SLEN;

    // K/V staging for k-tile index t: 4 gl_lds per wave (2 K + 2 V)
    auto stage = [&](int t, int buf) {
        const int kb = t * 64;                           // element offset
        #pragma unroll
        for (int q = 0; q < 2; ++q) {
            int r = (w * 2 + q) * 8 + kv_r;              // tile row 0..63
            gl_lds16(kgb + (size_t)(kb + r) * 128 + kv_c, &KT[buf][(w * 2 + q) * 1024]);
            gl_lds16(vgb + (size_t)r * 4096 + (size_t)kb * 2 + kv_c, &VT[buf][(w * 2 + q) * 1024]);
        }
    };
    auto loadmask = [&](int t, const int* mr, i32x4* m) {
        #pragma unroll
        for (int n = 0; n < 4; ++n)
            m[n] = __builtin_nontemporal_load((const i32x4*)(mr + t * 64 + n * 16 + lg * 4));
    };
    auto compress = [&](const i32x4* m, unsigned* pm) {
        #pragma unroll
        for (int n = 0; n < 4; ++n)
            pm[n] = (m[n][0] != 0 ? 1u : 0u) | (m[n][1] != 0 ? 2u : 0u)
                  | (m[n][2] != 0 ? 4u : 0u) | (m[n][3] != 0 ? 8u : 0u);
    };

    i32x4 rawA[4], rawB[4];    // per-group mask load buffers
    unsigned pm0[4], pm1[4];   // packed nibbles for the CURRENT tile

    // group bodies: per-n fused QK->exp->PV (p_n consumed immediately)
    auto body0 = [&](int cur) {
        #pragma unroll
        for (int n = 0; n < 4; ++n) {
            f32x4 s = {0, 0, 0, 0};
            #pragma unroll
            for (int t = 0; t < 2; ++t) {
                bf16x8 bk = *(const bf16x8*)&KT[cur][(n * 16 + lq) * 128 + ((t * 64 + lg * 16) ^ swzk)];
                s = __builtin_amdgcn_mfma_f32_16x16x32_bf16(bk, aq0[t], s, 0, 0, 0);
            }
            bf16x4 pn;
            #pragma unroll
            for (int i = 0; i < 4; ++i) {
                float pe = exp2f(s[i] * SCALE_LOG2E);
                pe = ((pm0[n] >> i) & 1u) ? 1.0f : pe;   // masked score 0 -> weight 1
                dpart0 += pe;
                pn[i] = (bf16)pe;
            }
            #pragma unroll
            for (int nn = 0; nn < 4; ++nn) {
                bf16x4 bv = *(const bf16x4*)&VT[cur][(nn * 16 + lq) * 128 + ((n * 32 + lg * 8) ^ swzk)];
                acc0[nn] = pv_mfma(pn, bv, acc0[nn]);
            }
        }
    };
    auto body1 = [&](int cur) {
        #pragma unroll
        for (int n = 0; n < 4; ++n) {
            f32x4 s = {0, 0, 0, 0};
            #pragma unroll
            for (int t = 0; t < 2; ++t) {
                bf16x8 bk = *(const bf16x8*)&KT[cur][(n * 16 + lq) * 128 + ((t * 64 + lg * 16) ^ swzk)];
                s = __builtin_amdgcn_mfma_f32_16x16x32_bf16(bk, aq1[t], s, 0, 0, 0);
            }
            bf16x4 pn;
            #pragma unroll
            for (int i = 0; i < 4; ++i) {
                float pe = exp2f(s[i] * SCALE_LOG2E);
                pe = ((pm1[n] >> i) & 1u) ? 1.0f : pe;
                dpart1 += pe;
                pn[i] = (bf16)pe;
            }
            #pragma unroll
            for (int nn = 0; nn < 4; ++nn) {
                bf16x4 bv = *(const bf16x4*)&VT[cur][(nn * 16 + lq) * 128 + ((n * 32 + lg * 8) ^ swzk)];
                acc1[nn] = pv_mfma(pn, bv, acc1[nn]);
            }
        }
    };
    auto tile_sync = [&]() {
        asm volatile("s_waitcnt vmcnt(0) lgkmcnt(0)" ::: "memory");
        __builtin_amdgcn_s_barrier();
        __builtin_amdgcn_sched_barrier(0);
    };

    // prologue
    loadmask(0, mrow0, rawA);
    loadmask(0, mrow1, rawB);
    __builtin_amdgcn_sched_barrier(0);
    stage(0, 0);
    __builtin_amdgcn_sched_barrier(0);
    compress(rawA, pm0);
    compress(rawB, pm1);
    tile_sync();

    int cur = 0;
    for (int kt = 0; kt < NT; ++kt) {
        const bool more = (kt + 1) < NT;                 // wave-uniform
        if (more) {
            loadmask(kt + 1, mrow0, rawA);               // masks first (older)
            loadmask(kt + 1, mrow1, rawB);
            __builtin_amdgcn_sched_barrier(0);
            stage(kt + 1, cur ^ 1);                      // gl_lds newest
        }
        __builtin_amdgcn_sched_barrier(0);
        body0(cur);
        body1(cur);
        __builtin_amdgcn_sched_barrier(0);               // pin compress below bodies
        if (more) {
            compress(rawA, pm0);                         // retires masks only
            compress(rawB, pm1);
            tile_sync();                                 // gl_lds landed under bodies
            cur ^= 1;
        }
    }

    // epilogue: per-group denom reduce + normalized write
    {
        float d = dpart0;
        d += __shfl_xor(d, 16, 64);
        d += __shfl_xor(d, 32, 64);
        float dinv = 1.0f / d;
        float di[4];
        #pragma unroll
        for (int i = 0; i < 4; ++i) di[i] = __shfl(dinv, lg * 4 + i, 64);
        float* op = out + ((size_t)bh * SLEN + qrow_w) * DH;
        #pragma unroll
        for (int n = 0; n < 4; ++n)
            #pragma unroll
            for (int i = 0; i < 4; ++i)
                op[(size_t)(lg * 4 + i) * DH + n * 16 + lq] = acc0[n][i] * di[i];
    }
    {
        float d = dpart1;
        d += __shfl_xor(d, 16, 64);
        d += __shfl_xor(d, 32, 64);
        float dinv = 1.0f / d;
        float di[4];
        #pragma unroll
        for (int i = 0; i < 4; ++i) di[i] = __shfl(dinv, lg * 4 + i, 64);
        float* op = out + ((size_t)bh * SLEN + qrow_w + 16) * DH;
        #pragma unroll
        for (int n = 0; n < 4; ++n)
            #pragma unroll
            for (int i = 0; i < 4; ++i)
                op[(size_t)(lg * 4 + i) * DH + n * 16 + lq] = acc1[n][i] * di[i];
    }
}

extern "C" void kernel_launch(void* const* d_in, const int* in_sizes, int n_in,
                              void* d_out, int out_size, void* d_ws, size_t ws_size,
                              hipStream_t stream) {
    const float* Q    = (const float*)d_in[0];
    const float* K    = (const float*)d_in[1];
    const float* V    = (const float*)d_in[2];
    const int*   mask = (const int*)d_in[3];
    float* out = (float*)d_out;

    bf16* Kb  = (bf16*)d_ws;                       // 16 MB
    bf16* Vtb = Kb + (size_t)NBH * SLEN * DH;      // 16 MB

    prep_kv_kernel<<<dim3(SLEN / 64, NBH), 256, 0, stream>>>(K, V, Kb, Vtb);
    attn_kernel<<<1024, 256, 0, stream>>>(Q, mask, Kb, Vtb, out);
}

// Round 16
// 305.393 us; speedup vs baseline: 2.6440x; 1.7841x over previous
//
#include <hip/hip_runtime.h>
#include <hip/hip_bf16.h>

typedef __bf16 bf16;
typedef __attribute__((ext_vector_type(8))) __bf16 bf16x8;
typedef __attribute__((ext_vector_type(4))) __bf16 bf16x4;
typedef __attribute__((ext_vector_type(4))) float f32x4;
typedef __attribute__((ext_vector_type(4))) int i32x4;
typedef __attribute__((ext_vector_type(4))) short s16x4;

constexpr int SLEN = 2048;
constexpr int DH = 64;
constexpr int NBH = 64;                      // B*H = 4*16
constexpr int NT = SLEN / 64;                // 32 k-tiles
constexpr float SCALE_LOG2E = 0.125f * 1.4426950408889634f;  // (1/sqrt(64)) * log2(e)

// ---- fused pre-pass: K fp32->bf16 (coalesced) + V fp32 [s][d] -> bf16 Vt [d][s] ----
__global__ __launch_bounds__(256) void prep_kv_kernel(
    const float* __restrict__ K, const float* __restrict__ V,
    bf16* __restrict__ Kb, bf16* __restrict__ Vt)
{
    __shared__ float t[64][65];
    const int bh = blockIdx.y;
    const int s0 = blockIdx.x * 64;
    const int tx = threadIdx.x & 63, ty = threadIdx.x >> 6;

    // V tile -> LDS
    const float* vp = V + ((size_t)bh * SLEN + s0) * DH;
    #pragma unroll
    for (int r = ty; r < 64; r += 4) t[r][tx] = vp[(size_t)r * DH + tx];

    // K cast (independent of LDS; overlaps the transpose latency)
    {
        const float* kp = K + ((size_t)bh * SLEN + s0) * DH;
        bf16* kbp = Kb + ((size_t)bh * SLEN + s0) * DH;
        int r = threadIdx.x >> 2, c = (threadIdx.x & 3) * 16;
        const float4* src = (const float4*)(kp + (size_t)r * DH + c);
        float4 a = src[0], b = src[1], c2 = src[2], d = src[3];
        bf16x8 o0, o1;
        o0[0]=(bf16)a.x;  o0[1]=(bf16)a.y;  o0[2]=(bf16)a.z;  o0[3]=(bf16)a.w;
        o0[4]=(bf16)b.x;  o0[5]=(bf16)b.y;  o0[6]=(bf16)b.z;  o0[7]=(bf16)b.w;
        o1[0]=(bf16)c2.x; o1[1]=(bf16)c2.y; o1[2]=(bf16)c2.z; o1[3]=(bf16)c2.w;
        o1[4]=(bf16)d.x;  o1[5]=(bf16)d.y;  o1[6]=(bf16)d.z;  o1[7]=(bf16)d.w;
        *(bf16x8*)(kbp + (size_t)r * DH + c)     = o0;
        *(bf16x8*)(kbp + (size_t)r * DH + c + 8) = o1;
    }

    __syncthreads();
    bf16* op = Vt + (size_t)bh * DH * SLEN + s0;
    #pragma unroll
    for (int r = ty; r < 64; r += 4) op[(size_t)r * SLEN + tx] = (bf16)t[tx][r];
}

// async global->LDS, 16B per lane, dest = wave-uniform base + lane*16
__device__ __forceinline__ void gl_lds16(const void* g, void* l) {
    __builtin_amdgcn_global_load_lds(
        (const __attribute__((address_space(1))) void*)g,
        (__attribute__((address_space(3))) void*)l, 16, 0, 0);
}

// 16x16x16 bf16 MFMA (instruction exists on gfx950: cdna4_isa §10).
__device__ __forceinline__ f32x4 pv_mfma(bf16x4 a, bf16x4 b, f32x4 c) {
#if __has_builtin(__builtin_amdgcn_mfma_f32_16x16x16bf16_1k)
    return __builtin_amdgcn_mfma_f32_16x16x16bf16_1k(
        __builtin_bit_cast(s16x4, a), __builtin_bit_cast(s16x4, b), c, 0, 0, 0);
#else
    f32x4 d;
    asm("s_nop 1\n\t"
        "v_mfma_f32_16x16x16_bf16 %0, %1, %2, %3\n\t"
        "s_nop 7"
        : "=v"(d) : "v"(a), "v"(b), "v"(c));
    return d;
#endif
}

// ---- main attention kernel (R12 verbatim — best measured: 305.8us) ----
// 4 waves, 64 q-rows/block, k-tiles of 64, LDS 32KB (KT+VT dbuf; PV consumes
// P from registers via 16x16x16 MFMA), launch_bounds(256,5) -> 5 blocks/CU.
// Mask: single raw[4] buffer; per tile compress (tile kt, loaded one tile
// ago) -> pm nibbles BEFORE issuing tile kt+1's mask loads; compress waits
// only on the OLDER mask loads (gl_lds stays in flight).
// Counted-vmcnt schedule: per tile {4 gl_lds, [compress], 4 mask loads};
// sync = s_waitcnt vmcnt(4) lgkmcnt(0) + s_barrier.
// K/V LDS rows swizzled byte^=(row&7)<<4 on the GLOBAL SOURCE side, mirrored
// on reads. XCD-bijective block swizzle (2048 blocks): XCD x owns bh 8x..8x+7.
// Swapped QK^T: lane (lq,lg) holds scores for q-row lq, k=n*16+lg*4+i.
// masked_fill is 0 (not -inf), |s|<=~7 -> unnormalized exp safe; one divide.
// 128-q-row variants (R13-R15) all lost to VGPR spill / occupancy trade:
// 807/708/545us vs this structure's 305.8us. Do not revisit without a
// fundamentally smaller per-row register footprint.
__global__ __launch_bounds__(256, 5) void attn_kernel(
    const float* __restrict__ Q, const int* __restrict__ mask,
    const bf16* __restrict__ Kb, const bf16* __restrict__ Vtb,
    float* __restrict__ out)
{
    __shared__ char KT[2][8192];
    __shared__ char VT[2][8192];

    // XCD-aware bijective swizzle (2048 blocks, 2048%8==0): XCD x owns bh 8x..8x+7
    const int h = blockIdx.x;
    const int logical = (h & 7) * 256 + (h >> 3);
    const int bh = logical >> 5;
    const int qbase = (logical & 31) * 64;
    const int tid = threadIdx.x;
    const int w = tid >> 6, l = tid & 63;
    const int lq = l & 15, lg = l >> 4;

    const char* kgb = (const char*)(Kb + (size_t)bh * SLEN * DH);      // rows 128B
    const char* vgb = (const char*)(Vtb + (size_t)bh * DH * SLEN);     // rows 4096B

    // staging geometry: lane covers (row octet kv_r, swizzled 16B col kv_c)
    const int kv_r = l >> 3;                             // 0..7
    const int kv_c = ((l & 7) * 16) ^ (kv_r << 4);

    // Q B-frags (q-col = lq, k = t*32+lg*8+j), hoisted fp32->bf16
    bf16x8 aq[2];
    {
        const float* qp = Q + ((size_t)bh * SLEN + qbase + w * 16 + lq) * DH + lg * 8;
        #pragma unroll
        for (int t = 0; t < 2; ++t) {
            float4 x = *(const float4*)(qp + t * 32);
            float4 y = *(const float4*)(qp + t * 32 + 4);
            bf16x8 f;
            f[0]=(bf16)x.x; f[1]=(bf16)x.y; f[2]=(bf16)x.z; f[3]=(bf16)x.w;
            f[4]=(bf16)y.x; f[5]=(bf16)y.y; f[6]=(bf16)y.z; f[7]=(bf16)y.w;
            aq[t] = f;
        }
    }

    f32x4 acc[4] = {{0,0,0,0},{0,0,0,0},{0,0,0,0},{0,0,0,0}};
    float dpart = 0.f;
    const int swzk = (lq & 7) << 4;      // read-side XOR, row%8 == lq%8

    const int* mrow = mask + ((size_t)bh * SLEN + qbase + w * 16 + lq) * SLEN;

    // K/V staging for k-tile index t: 4 gl_lds per wave (2 K + 2 V)
    auto stage = [&](int t, int buf) {
        const int kb = t * 64;                           // element offset
        #pragma unroll
        for (int q = 0; q < 2; ++q) {
            int r = (w * 2 + q) * 8 + kv_r;              // tile row 0..63
            gl_lds16(kgb + (size_t)(kb + r) * 128 + kv_c, &KT[buf][(w * 2 + q) * 1024]);
            gl_lds16(vgb + (size_t)r * 4096 + (size_t)kb * 2 + kv_c, &VT[buf][(w * 2 + q) * 1024]);
        }
    };
    auto loadmask = [&](int t, i32x4* m) {
        #pragma unroll
        for (int n = 0; n < 4; ++n)
            m[n] = __builtin_nontemporal_load((const i32x4*)(mrow + t * 64 + n * 16 + lg * 4));
    };
    // one k-tile of compute: LDS buf `cur`, packed mask nibbles pm[4]
    auto body = [&](int cur, const unsigned* pm) {
        // QK^T: S^T subtile n -> p[n] (bf16x4, q=lq, k=n*16+lg*4+i)
        bf16x4 p[4];
        #pragma unroll
        for (int n = 0; n < 4; ++n) {
            f32x4 s = {0, 0, 0, 0};
            #pragma unroll
            for (int t = 0; t < 2; ++t) {
                bf16x8 bk = *(const bf16x8*)&KT[cur][(n * 16 + lq) * 128 + ((t * 64 + lg * 16) ^ swzk)];
                s = __builtin_amdgcn_mfma_f32_16x16x32_bf16(bk, aq[t], s, 0, 0, 0);
            }
            #pragma unroll
            for (int i = 0; i < 4; ++i) {
                float pe = exp2f(s[i] * SCALE_LOG2E);
                pe = ((pm[n] >> i) & 1u) ? 1.0f : pe;    // masked score 0 -> weight 1
                dpart += pe;
                p[n][i] = (bf16)pe;
            }
        }
        // PV: acc[nn] += sum_n P_frag(n) x V_frag(nn,n), all in registers;
        // V B-frag = b64 read: row d = nn*16+lq, k-bytes n*32+lg*8 (^ swz)
        #pragma unroll
        for (int nn = 0; nn < 4; ++nn) {
            #pragma unroll
            for (int n = 0; n < 4; ++n) {
                bf16x4 bv = *(const bf16x4*)&VT[cur][(nn * 16 + lq) * 128 + ((n * 32 + lg * 8) ^ swzk)];
                acc[nn] = pv_mfma(p[n], bv, acc[nn]);
            }
        }
    };
    // counted sync: gl_lds (older) retired, DS pipe drained; 4 mask loads
    // (newest) stay in flight across the barrier.
    auto tile_sync = [&]() {
        asm volatile("s_waitcnt vmcnt(4) lgkmcnt(0)" ::: "memory");
        __builtin_amdgcn_s_barrier();
        __builtin_amdgcn_sched_barrier(0);
    };

    i32x4 raw[4];        // single mask load buffer (freed each tile by compress)
    unsigned pm[4];      // packed nibbles for the current tile

    // prologue: tile 0 -> buf0, mask0 -> raw
    stage(0, 0);
    __builtin_amdgcn_sched_barrier(0);   // keep mask loads newer than gl_lds
    loadmask(0, raw);
    tile_sync();

    int cur = 0;
    for (int kt = 0; kt < NT; ++kt) {
        const bool more = (kt + 1) < NT;                 // wave-uniform
        if (more) stage(kt + 1, cur ^ 1);                // K/V prefetch first
        __builtin_amdgcn_sched_barrier(0);
        // compress raw (tile kt, loaded one tile ago) -> pm; frees raw
        #pragma unroll
        for (int n = 0; n < 4; ++n)
            pm[n] = (raw[n][0] != 0 ? 1u : 0u) | (raw[n][1] != 0 ? 2u : 0u)
                  | (raw[n][2] != 0 ? 4u : 0u) | (raw[n][3] != 0 ? 8u : 0u);
        if (more) loadmask(kt + 1, raw);                 // next-tile masks, early
        __builtin_amdgcn_sched_barrier(0);
        body(cur, pm);
        if (more) { tile_sync(); cur ^= 1; }
    }

    // denom: lanes {lq, lq+16, lq+32, lq+48} hold partials for q-row lq
    dpart += __shfl_xor(dpart, 16, 64);
    dpart += __shfl_xor(dpart, 32, 64);
    float dinv = 1.0f / dpart;

    float di[4];
    #pragma unroll
    for (int i = 0; i < 4; ++i) di[i] = __shfl(dinv, lg * 4 + i, 64);

    float* op = out + ((size_t)bh * SLEN + qbase + w * 16) * DH;
    #pragma unroll
    for (int n = 0; n < 4; ++n) {
        #pragma unroll
        for (int i = 0; i < 4; ++i)
            op[(size_t)(lg * 4 + i) * DH + n * 16 + lq] = acc[n][i] * di[i];
    }
}

extern "C" void kernel_launch(void* const* d_in, const int* in_sizes, int n_in,
                              void* d_out, int out_size, void* d_ws, size_t ws_size,
                              hipStream_t stream) {
    const float* Q    = (const float*)d_in[0];
    const float* K    = (const float*)d_in[1];
    const float* V    = (const float*)d_in[2];
    const int*   mask = (const int*)d_in[3];
    float* out = (float*)d_out;

    bf16* Kb  = (bf16*)d_ws;                       // 16 MB
    bf16* Vtb = Kb + (size_t)NBH * SLEN * DH;      // 16 MB

    prep_kv_kernel<<<dim3(SLEN / 64, NBH), 256, 0, stream>>>(K, V, Kb, Vtb);
    attn_kernel<<<2048, 256, 0, stream>>>(Q, mask, Kb, Vtb, out);
}

// Round 17
// 300.732 us; speedup vs baseline: 2.6850x; 1.0155x over previous
//
#include <hip/hip_runtime.h>
#include <hip/hip_bf16.h>

typedef __bf16 bf16;
typedef __attribute__((ext_vector_type(8))) __bf16 bf16x8;
typedef __attribute__((ext_vector_type(4))) __bf16 bf16x4;
typedef __attribute__((ext_vector_type(4))) float f32x4;
typedef __attribute__((ext_vector_type(4))) int i32x4;
typedef __attribute__((ext_vector_type(4))) short s16x4;
typedef unsigned long long u64;

constexpr int SLEN = 2048;
constexpr int DH = 64;
constexpr int NBH = 64;                      // B*H = 4*16
constexpr int NT = SLEN / 64;                // 32 k-tiles
constexpr float SCALE_LOG2E = 0.125f * 1.4426950408889634f;  // (1/sqrt(64)) * log2(e)

// ---- fused pre-pass: K fp32->bf16 (coalesced) + V fp32 [s][d] -> bf16 Vt [d][s] ----
__global__ __launch_bounds__(256) void prep_kv_kernel(
    const float* __restrict__ K, const float* __restrict__ V,
    bf16* __restrict__ Kb, bf16* __restrict__ Vt)
{
    __shared__ float t[64][65];
    const int bh = blockIdx.y;
    const int s0 = blockIdx.x * 64;
    const int tx = threadIdx.x & 63, ty = threadIdx.x >> 6;

    // V tile -> LDS
    const float* vp = V + ((size_t)bh * SLEN + s0) * DH;
    #pragma unroll
    for (int r = ty; r < 64; r += 4) t[r][tx] = vp[(size_t)r * DH + tx];

    // K cast (independent of LDS; overlaps the transpose latency)
    {
        const float* kp = K + ((size_t)bh * SLEN + s0) * DH;
        bf16* kbp = Kb + ((size_t)bh * SLEN + s0) * DH;
        int r = threadIdx.x >> 2, c = (threadIdx.x & 3) * 16;
        const float4* src = (const float4*)(kp + (size_t)r * DH + c);
        float4 a = src[0], b = src[1], c2 = src[2], d = src[3];
        bf16x8 o0, o1;
        o0[0]=(bf16)a.x;  o0[1]=(bf16)a.y;  o0[2]=(bf16)a.z;  o0[3]=(bf16)a.w;
        o0[4]=(bf16)b.x;  o0[5]=(bf16)b.y;  o0[6]=(bf16)b.z;  o0[7]=(bf16)b.w;
        o1[0]=(bf16)c2.x; o1[1]=(bf16)c2.y; o1[2]=(bf16)c2.z; o1[3]=(bf16)c2.w;
        o1[4]=(bf16)d.x;  o1[5]=(bf16)d.y;  o1[6]=(bf16)d.z;  o1[7]=(bf16)d.w;
        *(bf16x8*)(kbp + (size_t)r * DH + c)     = o0;
        *(bf16x8*)(kbp + (size_t)r * DH + c + 8) = o1;
    }

    __syncthreads();
    bf16* op = Vt + (size_t)bh * DH * SLEN + s0;
    #pragma unroll
    for (int r = ty; r < 64; r += 4) op[(size_t)r * SLEN + tx] = (bf16)t[tx][r];
}

// async global->LDS, 16B per lane, dest = wave-uniform base + lane*16
__device__ __forceinline__ void gl_lds16(const void* g, void* l) {
    __builtin_amdgcn_global_load_lds(
        (const __attribute__((address_space(1))) void*)g,
        (__attribute__((address_space(3))) void*)l, 16, 0, 0);
}

// 16x16x16 bf16 MFMA (instruction exists on gfx950: cdna4_isa §10).
__device__ __forceinline__ f32x4 pv_mfma(bf16x4 a, bf16x4 b, f32x4 c) {
#if __has_builtin(__builtin_amdgcn_mfma_f32_16x16x16bf16_1k)
    return __builtin_amdgcn_mfma_f32_16x16x16bf16_1k(
        __builtin_bit_cast(s16x4, a), __builtin_bit_cast(s16x4, b), c, 0, 0, 0);
#else
    f32x4 d;
    asm("s_nop 1\n\t"
        "v_mfma_f32_16x16x16_bf16 %0, %1, %2, %3\n\t"
        "s_nop 7"
        : "=v"(d) : "v"(a), "v"(b), "v"(c));
    return d;
#endif
}

// ---- main attention kernel ----
// vs R16 (single variable): mask loads are now WAVE-CONTIGUOUS. Old layout:
// each instruction scattered 64 lanes over 16 rows x 64B segments (16
// transactions, half-L2-line each). New: instruction j covers rows j*4+
// (l>>4), ints (l&15)*4..+3 -> 4 x 256B segments per instruction (4x fewer,
// 4x larger). The (row,col)->lane redistribution happens in-register via
// __ballot: bit l' of ballot(raw_j[i]!=0) = mask(row j*4+(l'>>4), col
// (l'&15)*4+i); lane (lq,lg) needs bit (lq&3)*16+n*4+lg of ballot j=lq>>2.
// Ballots processed per-i (max 4 u64 live -> 8 SGPRs); pm[4] -> one pmall
// (bit n*4+i). Everything else identical to R16: 4 waves, 64 q-rows/block,
// 32KB LDS, (256,5) -> 5 blocks/CU, counted-vmcnt schedule {4 gl_lds then
// 4 mask loads, sync = vmcnt(4) lgkmcnt(0) + barrier}, K/V source-side XOR
// swizzle, XCD-bijective block swizzle, register-P PV via 16x16x16 MFMA.
// masked_fill is 0 (not -inf), |s|<=~7 -> unnormalized exp safe; one divide.
__global__ __launch_bounds__(256, 5) void attn_kernel(
    const float* __restrict__ Q, const int* __restrict__ mask,
    const bf16* __restrict__ Kb, const bf16* __restrict__ Vtb,
    float* __restrict__ out)
{
    __shared__ char KT[2][8192];
    __shared__ char VT[2][8192];

    // XCD-aware bijective swizzle (2048 blocks, 2048%8==0): XCD x owns bh 8x..8x+7
    const int h = blockIdx.x;
    const int logical = (h & 7) * 256 + (h >> 3);
    const int bh = logical >> 5;
    const int qbase = (logical & 31) * 64;
    const int tid = threadIdx.x;
    const int w = tid >> 6, l = tid & 63;
    const int lq = l & 15, lg = l >> 4;

    const char* kgb = (const char*)(Kb + (size_t)bh * SLEN * DH);      // rows 128B
    const char* vgb = (const char*)(Vtb + (size_t)bh * DH * SLEN);     // rows 4096B

    // staging geometry: lane covers (row octet kv_r, swizzled 16B col kv_c)
    const int kv_r = l >> 3;                             // 0..7
    const int kv_c = ((l & 7) * 16) ^ (kv_r << 4);

    // Q B-frags (q-col = lq, k = t*32+lg*8+j), hoisted fp32->bf16
    bf16x8 aq[2];
    {
        const float* qp = Q + ((size_t)bh * SLEN + qbase + w * 16 + lq) * DH + lg * 8;
        #pragma unroll
        for (int t = 0; t < 2; ++t) {
            float4 x = *(const float4*)(qp + t * 32);
            float4 y = *(const float4*)(qp + t * 32 + 4);
            bf16x8 f;
            f[0]=(bf16)x.x; f[1]=(bf16)x.y; f[2]=(bf16)x.z; f[3]=(bf16)x.w;
            f[4]=(bf16)y.x; f[5]=(bf16)y.y; f[6]=(bf16)y.z; f[7]=(bf16)y.w;
            aq[t] = f;
        }
    }

    f32x4 acc[4] = {{0,0,0,0},{0,0,0,0},{0,0,0,0},{0,0,0,0}};
    float dpart = 0.f;
    const int swzk = (lq & 7) << 4;      // read-side XOR, row%8 == lq%8

    // contiguous mask base: lane l covers row-in-quartet (l>>4), ints (l&15)*4
    const int* mrowc = mask + ((size_t)bh * SLEN + qbase + w * 16 + (l >> 4)) * SLEN
                            + (l & 15) * 4;

    // K/V staging for k-tile index t: 4 gl_lds per wave (2 K + 2 V)
    auto stage = [&](int t, int buf) {
        const int kb = t * 64;                           // element offset
        #pragma unroll
        for (int q = 0; q < 2; ++q) {
            int r = (w * 2 + q) * 8 + kv_r;              // tile row 0..63
            gl_lds16(kgb + (size_t)(kb + r) * 128 + kv_c, &KT[buf][(w * 2 + q) * 1024]);
            gl_lds16(vgb + (size_t)r * 4096 + (size_t)kb * 2 + kv_c, &VT[buf][(w * 2 + q) * 1024]);
        }
    };
    // wave-contiguous mask loads: instruction j = rows qbase+w*16+j*4..+3,
    // 1KB contiguous per wave (4 x 256B row-segments)
    auto loadmask = [&](int t, i32x4* m) {
        #pragma unroll
        for (int j = 0; j < 4; ++j)
            m[j] = __builtin_nontemporal_load(
                (const i32x4*)(mrowc + (size_t)j * 4 * SLEN + t * 64));
    };
    // ballot-redistribute raw (this tile's masks, loaded last round) -> pmall
    // pmall bit (n*4+i) = mask(row lq, col n*16+lg*4+i) != 0
    const int jsel = lq >> 2;
    const int shb = (lq & 3) * 16 + lg;
    auto extract = [&](const i32x4* m) -> unsigned {
        unsigned pmall = 0;
        #pragma unroll
        for (int i = 0; i < 4; ++i) {
            u64 b0 = __ballot(m[0][i] != 0);
            u64 b1 = __ballot(m[1][i] != 0);
            u64 b2 = __ballot(m[2][i] != 0);
            u64 b3 = __ballot(m[3][i] != 0);
            u64 b = jsel == 0 ? b0 : jsel == 1 ? b1 : jsel == 2 ? b2 : b3;
            unsigned lo = (unsigned)(b >> shb) & 0x1111u;  // bits n*4, n=0..3
            pmall |= lo << i;
        }
        return pmall;
    };
    // one k-tile of compute: LDS buf `cur`, packed mask bits pmall
    auto body = [&](int cur, unsigned pmall) {
        // QK^T: S^T subtile n -> p[n] (bf16x4, q=lq, k=n*16+lg*4+i)
        bf16x4 p[4];
        #pragma unroll
        for (int n = 0; n < 4; ++n) {
            f32x4 s = {0, 0, 0, 0};
            #pragma unroll
            for (int t = 0; t < 2; ++t) {
                bf16x8 bk = *(const bf16x8*)&KT[cur][(n * 16 + lq) * 128 + ((t * 64 + lg * 16) ^ swzk)];
                s = __builtin_amdgcn_mfma_f32_16x16x32_bf16(bk, aq[t], s, 0, 0, 0);
            }
            #pragma unroll
            for (int i = 0; i < 4; ++i) {
                float pe = exp2f(s[i] * SCALE_LOG2E);
                pe = ((pmall >> (n * 4 + i)) & 1u) ? 1.0f : pe;  // masked -> weight 1
                dpart += pe;
                p[n][i] = (bf16)pe;
            }
        }
        // PV: acc[nn] += sum_n P_frag(n) x V_frag(nn,n), all in registers;
        // V B-frag = b64 read: row d = nn*16+lq, k-bytes n*32+lg*8 (^ swz)
        #pragma unroll
        for (int nn = 0; nn < 4; ++nn) {
            #pragma unroll
            for (int n = 0; n < 4; ++n) {
                bf16x4 bv = *(const bf16x4*)&VT[cur][(nn * 16 + lq) * 128 + ((n * 32 + lg * 8) ^ swzk)];
                acc[nn] = pv_mfma(p[n], bv, acc[nn]);
            }
        }
    };
    // counted sync: gl_lds (older) retired, DS pipe drained; 4 mask loads
    // (newest) stay in flight across the barrier.
    auto tile_sync = [&]() {
        asm volatile("s_waitcnt vmcnt(4) lgkmcnt(0)" ::: "memory");
        __builtin_amdgcn_s_barrier();
        __builtin_amdgcn_sched_barrier(0);
    };

    i32x4 raw[4];        // single mask load buffer (freed each tile by extract)

    // prologue: tile 0 -> buf0, mask0 -> raw
    stage(0, 0);
    __builtin_amdgcn_sched_barrier(0);   // keep mask loads newer than gl_lds
    loadmask(0, raw);
    tile_sync();

    int cur = 0;
    for (int kt = 0; kt < NT; ++kt) {
        const bool more = (kt + 1) < NT;                 // wave-uniform
        if (more) stage(kt + 1, cur ^ 1);                // K/V prefetch first
        __builtin_amdgcn_sched_barrier(0);
        // extract raw (tile kt, loaded one tile ago) -> pmall; frees raw
        unsigned pmall = extract(raw);
        if (more) loadmask(kt + 1, raw);                 // next-tile masks, early
        __builtin_amdgcn_sched_barrier(0);
        body(cur, pmall);
        if (more) { tile_sync(); cur ^= 1; }
    }

    // denom: lanes {lq, lq+16, lq+32, lq+48} hold partials for q-row lq
    dpart += __shfl_xor(dpart, 16, 64);
    dpart += __shfl_xor(dpart, 32, 64);
    float dinv = 1.0f / dpart;

    float di[4];
    #pragma unroll
    for (int i = 0; i < 4; ++i) di[i] = __shfl(dinv, lg * 4 + i, 64);

    float* op = out + ((size_t)bh * SLEN + qbase + w * 16) * DH;
    #pragma unroll
    for (int n = 0; n < 4; ++n) {
        #pragma unroll
        for (int i = 0; i < 4; ++i)
            op[(size_t)(lg * 4 + i) * DH + n * 16 + lq] = acc[n][i] * di[i];
    }
}

extern "C" void kernel_launch(void* const* d_in, const int* in_sizes, int n_in,
                              void* d_out, int out_size, void* d_ws, size_t ws_size,
                              hipStream_t stream) {
    const float* Q    = (const float*)d_in[0];
    const float* K    = (const float*)d_in[1];
    const float* V    = (const float*)d_in[2];
    const int*   mask = (const int*)d_in[3];
    float* out = (float*)d_out;

    bf16* Kb  = (bf16*)d_ws;                       // 16 MB
    bf16* Vtb = Kb + (size_t)NBH * SLEN * DH;      // 16 MB

    prep_kv_kernel<<<dim3(SLEN / 64, NBH), 256, 0, stream>>>(K, V, Kb, Vtb);
    attn_kernel<<<2048, 256, 0, stream>>>(Q, mask, Kb, Vtb, out);
}